// Round 6
// baseline (413.973 us; speedup 1.0000x reference)
//
#include <hip/hip_runtime.h>

// ProbAttention on MI355X (gfx950). Inputs/outputs fp32; compute in bf16 MFMA
// (mfma_f32_16x16x32_bf16, fp32 accumulate). B=8, L=4096, D=512, H=8, DK=64,
// S=512, CONV_K=3, POOL=2.
//
// attn v8: same per-wave algorithm as v7 (v4 softmax numerics, two-half P/PV
// round-trip), re-tiled to 512 threads / 8 waves / M=256 q-rows per block.
// Evidence: v4 (70,656 B LDS), v6, v7 (54,272 B) ALL pinned at ~21.6%
// occupancy = 2 blocks x 4 waves = 2 waves/SIMD — the 3rd block never fit
// (3 x 54,272 leaves only 1 KB slack; any runtime LDS reservation kills it),
// and at 2 waves/SIMD the per-chunk serial chain can't be hidden (MfmaUtil 16,
// VALUBusy 32, ~50% stall). v8 shares one K/V chunk across 8 waves:
// LDS = 18,432 (Ks) + 17,408 (Vs) + 36,864 (Pp[256][72]) = 72,704 B
// -> 2 blocks/CU with 18 KB slack = 16 waves/CU = 4 waves/SIMD (2x v7).
// Per-wave numerics byte-identical to v7 (each wave owns 32 q-rows).

typedef __attribute__((ext_vector_type(8))) short  short8;
typedef __attribute__((ext_vector_type(4))) short  short4b;
typedef __attribute__((ext_vector_type(4))) float  f32x4;

#define LSEQ   4096
#define SK     512
#define EDIM   512
#define LPAD   4098            // L + 2
#define PADROW 2098176         // LPAD * 512 (shorts)

static __device__ __forceinline__ float bf2f(unsigned short h) {
    union { unsigned int u; float f; } v; v.u = ((unsigned int)h) << 16; return v.f;
}
static __device__ __forceinline__ unsigned short f2bf(float f) {
    union { float f; unsigned int u; } v; v.f = f;
    unsigned int r = (v.u + 0x7fffu + ((v.u >> 16) & 1u)) >> 16;
    return (unsigned short)r;
}

// ---------------------------------------------------------------- fp32 -> bf16
__global__ __launch_bounds__(256)
void cvt_bf16(const float* __restrict__ src, unsigned short* __restrict__ dst)
{
    const size_t i = ((size_t)blockIdx.x * 256 + threadIdx.x) * 8;
    const float4 a = *(const float4*)(src + i);
    const float4 b = *(const float4*)(src + i + 4);
    short8 o;
    o[0] = (short)f2bf(a.x); o[1] = (short)f2bf(a.y);
    o[2] = (short)f2bf(a.z); o[3] = (short)f2bf(a.w);
    o[4] = (short)f2bf(b.x); o[5] = (short)f2bf(b.y);
    o[6] = (short)f2bf(b.z); o[7] = (short)f2bf(b.w);
    *(short8*)(dst + i) = o;
}

// ---------------------------------------------------------------- transpose fp32 -> bf16
__global__ __launch_bounds__(256)
void tr_f32_bf16(unsigned short* __restrict__ dst, const float* __restrict__ src,
                 int R, int C)
{
    __shared__ unsigned short T[64][72];
    const int t  = threadIdx.x;
    const int r0 = blockIdx.y * 64, c0 = blockIdx.x * 64;
    const int row = t >> 2, cg = (t & 3) * 16;
    const float* s = src + (size_t)(r0 + row) * C + c0 + cg;
    const float4 f0 = *(const float4*)s;
    const float4 f1 = *(const float4*)(s + 4);
    const float4 f2 = *(const float4*)(s + 8);
    const float4 f3 = *(const float4*)(s + 12);
    T[row][cg + 0]  = f2bf(f0.x); T[row][cg + 1]  = f2bf(f0.y);
    T[row][cg + 2]  = f2bf(f0.z); T[row][cg + 3]  = f2bf(f0.w);
    T[row][cg + 4]  = f2bf(f1.x); T[row][cg + 5]  = f2bf(f1.y);
    T[row][cg + 6]  = f2bf(f1.z); T[row][cg + 7]  = f2bf(f1.w);
    T[row][cg + 8]  = f2bf(f2.x); T[row][cg + 9]  = f2bf(f2.y);
    T[row][cg + 10] = f2bf(f2.z); T[row][cg + 11] = f2bf(f2.w);
    T[row][cg + 12] = f2bf(f3.x); T[row][cg + 13] = f2bf(f3.y);
    T[row][cg + 14] = f2bf(f3.z); T[row][cg + 15] = f2bf(f3.w);
    __syncthreads();
    unsigned short* d = dst + (size_t)(c0 + row) * R + r0 + cg;
    short8 o0, o1;
    #pragma unroll
    for (int k = 0; k < 8; ++k) o0[k] = (short)T[cg + k][row];
    #pragma unroll
    for (int k = 0; k < 8; ++k) o1[k] = (short)T[cg + 8 + k][row];
    *(short8*)d       = o0;
    *(short8*)(d + 8) = o1;
}

// ---------------------------------------------------------------- transpose bf16
__global__ __launch_bounds__(256)
void tr_bf16(unsigned short* __restrict__ dst, const unsigned short* __restrict__ src,
             int R, int C)
{
    __shared__ unsigned short T[64][72];
    const size_t bofs = (size_t)blockIdx.z * (size_t)R * (size_t)C;
    src += bofs; dst += bofs;
    const int t  = threadIdx.x;
    const int r0 = blockIdx.y * 64, c0 = blockIdx.x * 64;
    const int row = t >> 2, cg = (t & 3) * 16;
    const unsigned short* s = src + (size_t)(r0 + row) * C + c0 + cg;
    *(short8*)&T[row][cg]     = *(const short8*)s;
    *(short8*)&T[row][cg + 8] = *(const short8*)(s + 8);
    __syncthreads();
    unsigned short* d = dst + (size_t)(c0 + row) * R + r0 + cg;
    short8 o0, o1;
    #pragma unroll
    for (int k = 0; k < 8; ++k) o0[k] = (short)T[cg + k][row];
    #pragma unroll
    for (int k = 0; k < 8; ++k) o1[k] = (short)T[cg + 8 + k][row];
    *(short8*)d       = o0;
    *(short8*)(d + 8) = o1;
}

// ---------------------------------------------------------------- gather rows (bf16)
__global__ __launch_bounds__(256)
void gather_rows(const unsigned short* __restrict__ xb, const int* __restrict__ sidx,
                 unsigned short* __restrict__ xkg, unsigned short* __restrict__ xvg)
{
    const int blk = blockIdx.x;
    const int b = blk >> 9, j = blk & 511;
    const int t = threadIdx.x;
    int qv = sidx[j];               qv = qv < 0 ? 0 : (qv > LSEQ - 1 ? LSEQ - 1 : qv);
    int cv = qv < SK - 1 ? qv : SK - 1;
    int pv = sidx[cv];              pv = pv < 0 ? 0 : (pv > LSEQ - 1 ? LSEQ - 1 : pv);
    const unsigned int* xs = (const unsigned int*)xb;
    unsigned int* kd = (unsigned int*)xkg;
    unsigned int* vd = (unsigned int*)xvg;
    const size_t dst = ((size_t)b * SK + j) * 256 + t;
    kd[dst] = xs[((size_t)b * LSEQ + pv) * 256 + t];
    vd[dst] = xs[((size_t)b * LSEQ + qv) * 256 + t];
}

// ---------------------------------------------------------------- zero pad rows
__global__ __launch_bounds__(256)
void zero_pad(unsigned short* __restrict__ attpad)
{
    const int i = blockIdx.x * 256 + threadIdx.x;   // 0..4095
    const int b = i >> 9, c = i & 511;
    attpad[(size_t)b * PADROW + c] = 0;
    attpad[(size_t)b * PADROW + (size_t)(LPAD - 1) * 512 + c] = 0;
}

// ---------------------------------------------------------------- GEMM 128x128x32
// MODE 0: bf16 store. MODE 1: conv epilogue (+bias, ELU, MaxPool2 -> bf16).
// MODE 2: +bias, fp32 store.
template<int MODE>
__global__ __launch_bounds__(256)
void gemm128(const unsigned short* __restrict__ A, const unsigned short* __restrict__ Bt,
             const float* __restrict__ bias, void* __restrict__ Cout, int K)
{
    __shared__ unsigned short As[128 * 40];
    __shared__ unsigned short Bs[128 * 40];
    const int t    = threadIdx.x;
    const int n0   = blockIdx.x * 128;
    const int m0   = blockIdx.y * 128;
    const int srow = t >> 1, scg = (t & 1) * 16;
    const int lane = t & 63, wv = t >> 6;
    const int q = lane >> 4, ln = lane & 15;
    const int wm = (wv & 1) * 64, wn = (wv >> 1) * 64;

    const unsigned short* abase;
    if (MODE == 1) {
        const int gr = m0 + srow;
        abase = A + (size_t)(gr >> 12) * PADROW + (size_t)(gr & 4095) * 512;
    } else {
        abase = A + (size_t)(m0 + srow) * K;
    }
    const unsigned short* bbase = Bt + (size_t)(n0 + srow) * K;

    const f32x4 zero = {0.f, 0.f, 0.f, 0.f};
    f32x4 acc[4][4];
    #pragma unroll
    for (int i = 0; i < 4; ++i)
        #pragma unroll
        for (int j = 0; j < 4; ++j) acc[i][j] = zero;

    short8 av0 = *(const short8*)(abase + scg);
    short8 av1 = *(const short8*)(abase + scg + 8);
    short8 bv0 = *(const short8*)(bbase + scg);
    short8 bv1 = *(const short8*)(bbase + scg + 8);

    for (int k0 = 0; k0 < K; k0 += 32) {
        __syncthreads();
        *(short8*)&As[srow * 40 + scg]     = av0;
        *(short8*)&As[srow * 40 + scg + 8] = av1;
        *(short8*)&Bs[srow * 40 + scg]     = bv0;
        *(short8*)&Bs[srow * 40 + scg + 8] = bv1;
        __syncthreads();
        if (k0 + 32 < K) {
            av0 = *(const short8*)(abase + k0 + 32 + scg);
            av1 = *(const short8*)(abase + k0 + 32 + scg + 8);
            bv0 = *(const short8*)(bbase + k0 + 32 + scg);
            bv1 = *(const short8*)(bbase + k0 + 32 + scg + 8);
        }
        short8 af[4], bf[4];
        #pragma unroll
        for (int mt = 0; mt < 4; ++mt)
            af[mt] = *(const short8*)&As[(wm + mt * 16 + ln) * 40 + q * 8];
        #pragma unroll
        for (int nt = 0; nt < 4; ++nt)
            bf[nt] = *(const short8*)&Bs[(wn + nt * 16 + ln) * 40 + q * 8];
        #pragma unroll
        for (int mt = 0; mt < 4; ++mt)
            #pragma unroll
            for (int nt = 0; nt < 4; ++nt)
                acc[mt][nt] = __builtin_amdgcn_mfma_f32_16x16x32_bf16(af[mt], bf[nt], acc[mt][nt], 0, 0, 0);
    }

    if (MODE == 0) {
        unsigned short* C = (unsigned short*)Cout;
        #pragma unroll
        for (int mt = 0; mt < 4; ++mt)
            #pragma unroll
            for (int r = 0; r < 4; ++r) {
                const int grow = m0 + wm + mt * 16 + q * 4 + r;
                unsigned short* cp = C + (size_t)grow * 512 + n0 + wn + ln;
                #pragma unroll
                for (int nt = 0; nt < 4; ++nt) cp[nt * 16] = f2bf(acc[mt][nt][r]);
            }
    } else if (MODE == 2) {
        float* C = (float*)Cout;
        float bb[4];
        #pragma unroll
        for (int nt = 0; nt < 4; ++nt) bb[nt] = bias[n0 + wn + nt * 16 + ln];
        #pragma unroll
        for (int mt = 0; mt < 4; ++mt)
            #pragma unroll
            for (int r = 0; r < 4; ++r) {
                const int grow = m0 + wm + mt * 16 + q * 4 + r;
                float* cp = C + (size_t)grow * 512 + n0 + wn + ln;
                #pragma unroll
                for (int nt = 0; nt < 4; ++nt) cp[nt * 16] = acc[mt][nt][r] + bb[nt];
            }
    } else { // MODE 1
        unsigned short* C = (unsigned short*)Cout;
        float bb[4];
        #pragma unroll
        for (int nt = 0; nt < 4; ++nt) bb[nt] = bias[n0 + wn + nt * 16 + ln];
        #pragma unroll
        for (int mt = 0; mt < 4; ++mt) {
            const int grow = m0 + wm + mt * 16 + q * 4;
            const int b = grow >> 12, l = grow & 4095;
            unsigned short* cp = C + ((size_t)b * 2048 + (l >> 1)) * 512 + n0 + wn + ln;
            #pragma unroll
            for (int nt = 0; nt < 4; ++nt) {
                float v0 = acc[mt][nt][0] + bb[nt]; v0 = v0 > 0.f ? v0 : __expf(v0) - 1.f;
                float v1 = acc[mt][nt][1] + bb[nt]; v1 = v1 > 0.f ? v1 : __expf(v1) - 1.f;
                float v2 = acc[mt][nt][2] + bb[nt]; v2 = v2 > 0.f ? v2 : __expf(v2) - 1.f;
                float v3 = acc[mt][nt][3] + bb[nt]; v3 = v3 > 0.f ? v3 : __expf(v3) - 1.f;
                cp[nt * 16]       = f2bf(fmaxf(v0, v1));
                cp[512 + nt * 16] = f2bf(fmaxf(v2, v3));
            }
        }
    }
}

// ---------------------------------------------------------------- fused attention v8
// grid (L/256, H, B), 512 threads = 8 waves; wave w owns 32 q-rows (2 tiles).
// S in 4 chunks of 128, online softmax (v4 numerics: running max, __expf,
// x0.125 post-MFMA, f2bf pack, alpha O-rescale). K chunk (128x64) and V chunk
// (64x128) staged in LDS, SHARED by all 8 waves; next chunk register-
// prefetched during softmax/PV (2 short8 K + 2 short8 V per thread).
// P round-trip through wave-private Pp rows in two 64-wide halves (same-wave
// DS ops complete in order — validated hazard class).
// LDS = 18,432 + 17,408 + 36,864 = 72,704 B -> 2 blocks/CU (18 KB slack)
// = 16 waves/CU = 4 waves/SIMD, 2x the residency of the 256-thread tiling
// (which was stuck at 2 blocks x 4 waves; 3rd block never fit at 1 KB slack).
__global__ __launch_bounds__(512, 2)
void attn_fused(const unsigned short* __restrict__ xb, const unsigned short* __restrict__ WqT,
                const unsigned short* __restrict__ Kg, const unsigned short* __restrict__ Vt,
                unsigned short* __restrict__ attpad)
{
    __shared__ unsigned short Ks[128][72];
    __shared__ unsigned short Vs[64][136];
    __shared__ unsigned short Pp[256][72];   // P half-chunk; also Q round-trip
    const int t = threadIdx.x;
    const int wv = t >> 6, lane = t & 63, q = lane >> 4, ln = lane & 15;
    const int l0 = blockIdx.x * 256, h = blockIdx.y, b = blockIdx.z;
    const int qr0 = wv * 32;
    const f32x4 zero = {0.f, 0.f, 0.f, 0.f};

    // staging maps (512 threads: 16 shorts of K and V each)
    const unsigned short* kgb = Kg + (size_t)b * SK * 512 + h * 64;        // + s*512 + e
    const unsigned short* vtb = Vt + ((size_t)(b * EDIM + h * 64)) * SK;   // + d*SK + s
    const int ksr = t >> 2, ksc = (t & 3) * 16;    // K: row s (0..127), 16-short quarter
    const int vsr = t >> 3, vsc = (t & 7) * 16;    // V: row d (0..63), 16-short eighth

    // prefetch chunk 0 (flies during Q projection)
    short8 kp0, kp1, vp0, vp1;
    {
        const unsigned short* ks = kgb + (size_t)ksr * 512 + ksc;
        kp0 = *(const short8*)ks;  kp1 = *(const short8*)(ks + 8);
        const unsigned short* vs = vtb + (size_t)vsr * SK + vsc;
        vp0 = *(const short8*)vs;  vp1 = *(const short8*)(vs + 8);
    }

    // --- Q projection: rows qr0 + g*16 + ln (g=0,1), 64 head cols, k=512
    f32x4 qacc[2][4];
    #pragma unroll
    for (int g = 0; g < 2; ++g)
        #pragma unroll
        for (int nt = 0; nt < 4; ++nt) qacc[g][nt] = zero;
    const unsigned short* xr0 = xb + ((size_t)(b * LSEQ + l0 + qr0 + ln)) * 512 + q * 8;
    const unsigned short* xr1 = xr0 + (size_t)16 * 512;
    const unsigned short* wqp = WqT + ((size_t)(h * 64 + ln)) * 512 + q * 8;
    for (int ks = 0; ks < 16; ++ks) {
        const short8 ax0 = *(const short8*)(xr0 + ks * 32);
        const short8 ax1 = *(const short8*)(xr1 + ks * 32);
        #pragma unroll
        for (int nt = 0; nt < 4; ++nt) {
            const short8 bw = *(const short8*)(wqp + nt * 16 * 512 + ks * 32);
            qacc[0][nt] = __builtin_amdgcn_mfma_f32_16x16x32_bf16(ax0, bw, qacc[0][nt], 0, 0, 0);
            qacc[1][nt] = __builtin_amdgcn_mfma_f32_16x16x32_bf16(ax1, bw, qacc[1][nt], 0, 0, 0);
        }
    }
    #pragma unroll
    for (int g = 0; g < 2; ++g)
        #pragma unroll
        for (int nt = 0; nt < 4; ++nt)
            #pragma unroll
            for (int r = 0; r < 4; ++r)
                Pp[qr0 + g * 16 + q * 4 + r][nt * 16 + ln] = f2bf(qacc[g][nt][r]);
    asm volatile("s_waitcnt lgkmcnt(0)" ::: "memory");   // wave-private round trip
    short8 bq[2][2];
    #pragma unroll
    for (int g = 0; g < 2; ++g) {
        bq[g][0] = *(const short8*)&Pp[qr0 + g * 16 + ln][q * 8];
        bq[g][1] = *(const short8*)&Pp[qr0 + g * 16 + ln][q * 8 + 32];
    }

    // --- flash state (per q-col = ln, per group g; replicated across quads)
    float m_run[2] = {-1e30f, -1e30f}, l_run[2] = {0.f, 0.f};
    f32x4 o[2][4];
    #pragma unroll
    for (int g = 0; g < 2; ++g)
        #pragma unroll
        for (int j = 0; j < 4; ++j) o[g][j] = zero;

    for (int c = 0; c < 4; ++c) {
        // store staged chunk (regs were prefetched)
        *(short8*)&Ks[ksr][ksc]     = kp0;  *(short8*)&Ks[ksr][ksc + 8] = kp1;
        *(short8*)&Vs[vsr][vsc]     = vp0;  *(short8*)&Vs[vsr][vsc + 8] = vp1;
        __syncthreads();   // A: Ks/Vs ready

        // scores (transposed): St[s = mt*16+quad*4+r][qcol = g*16+ln]
        f32x4 st[8][2];
        #pragma unroll
        for (int mt = 0; mt < 8; ++mt) {
            const short8 ak0 = *(const short8*)&Ks[mt * 16 + ln][q * 8];
            const short8 ak1 = *(const short8*)&Ks[mt * 16 + ln][q * 8 + 32];
            #pragma unroll
            for (int g = 0; g < 2; ++g) {
                f32x4 a = zero;
                a = __builtin_amdgcn_mfma_f32_16x16x32_bf16(ak0, bq[g][0], a, 0, 0, 0);
                a = __builtin_amdgcn_mfma_f32_16x16x32_bf16(ak1, bq[g][1], a, 0, 0, 0);
                #pragma unroll
                for (int r = 0; r < 4; ++r) a[r] *= 0.125f;
                st[mt][g] = a;
            }
        }

        // running max + alpha (full chunk, before any P/PV of this chunk)
        float alpha_[2], mcur[2], ls[2] = {0.f, 0.f};
        #pragma unroll
        for (int g = 0; g < 2; ++g) {
            float mx = st[0][g][0];
            #pragma unroll
            for (int mt = 0; mt < 8; ++mt)
                #pragma unroll
                for (int r = 0; r < 4; ++r) mx = fmaxf(mx, st[mt][g][r]);
            mx = fmaxf(mx, __shfl_xor(mx, 16));
            mx = fmaxf(mx, __shfl_xor(mx, 32));
            const float m_new = fmaxf(m_run[g], mx);
            alpha_[g] = __expf(m_run[g] - m_new);
            m_run[g] = m_new;
            mcur[g] = m_new;
        }

        // rescale O (rows q' = quad*4+r of tile g)
        #pragma unroll
        for (int g = 0; g < 2; ++g) {
            #pragma unroll
            for (int r = 0; r < 4; ++r) {
                const float ab = __shfl(alpha_[g], q * 4 + r);
                #pragma unroll
                for (int j = 0; j < 4; ++j) o[g][j][r] *= ab;
            }
        }

        // two 64-wide halves: exp -> pack -> Pp -> PV
        #pragma unroll
        for (int hh = 0; hh < 2; ++hh) {
            #pragma unroll
            for (int mtl = 0; mtl < 4; ++mtl) {
                const int mt = hh * 4 + mtl;
                #pragma unroll
                for (int g = 0; g < 2; ++g) {
                    short4b p4;
                    #pragma unroll
                    for (int r = 0; r < 4; ++r) {
                        const float p = __expf(st[mt][g][r] - mcur[g]);
                        ls[g] += p;
                        p4[r] = (short)f2bf(p);
                    }
                    *(short4b*)&Pp[qr0 + g * 16 + ln][mtl * 16 + q * 4] = p4;
                }
            }

            // prefetch next chunk into regs (overlaps both PV halves)
            if (hh == 0 && c < 3) {
                const unsigned short* ks = kgb + (size_t)((c + 1) * 128 + ksr) * 512 + ksc;
                kp0 = *(const short8*)ks;  kp1 = *(const short8*)(ks + 8);
                const unsigned short* vs = vtb + (size_t)vsr * SK + (c + 1) * 128 + vsc;
                vp0 = *(const short8*)vs;  vp1 = *(const short8*)(vs + 8);
            }

            asm volatile("s_waitcnt lgkmcnt(0)" ::: "memory");   // P visible to wave

            // PV half: A = P rows (q), B = Vs rows (d), k = 64
            #pragma unroll
            for (int ks2 = 0; ks2 < 2; ++ks2) {
                const short8 ap0 = *(const short8*)&Pp[qr0 + ln][ks2 * 32 + q * 8];
                const short8 ap1 = *(const short8*)&Pp[qr0 + 16 + ln][ks2 * 32 + q * 8];
                #pragma unroll
                for (int j = 0; j < 4; ++j) {
                    const short8 bv = *(const short8*)&Vs[j * 16 + ln][(hh * 2 + ks2) * 32 + q * 8];
                    o[0][j] = __builtin_amdgcn_mfma_f32_16x16x32_bf16(ap0, bv, o[0][j], 0, 0, 0);
                    o[1][j] = __builtin_amdgcn_mfma_f32_16x16x32_bf16(ap1, bv, o[1][j], 0, 0, 0);
                }
            }
            // hh=1 Pp writes cannot pass hh=0 Pp reads: same-wave DS ops are
            // processed in order, and the compiler sees the alias.
        }

        // fold chunk l into running l
        #pragma unroll
        for (int g = 0; g < 2; ++g) {
            float s2 = ls[g];
            s2 += __shfl_xor(s2, 16);
            s2 += __shfl_xor(s2, 32);
            l_run[g] = l_run[g] * alpha_[g] + s2;
        }
        __syncthreads();   // B: Ks/Vs reads done before restage
    }

    // epilogue: scale by 1/l, store rows l0+qr0+g*16+q*4+r (+1 pad offset)
    #pragma unroll
    for (int g = 0; g < 2; ++g) {
        const float li = 1.f / l_run[g];
        #pragma unroll
        for (int r = 0; r < 4; ++r) {
            const float ib = __shfl(li, q * 4 + r);
            const int rl = qr0 + g * 16 + q * 4 + r;
            #pragma unroll
            for (int j = 0; j < 4; ++j)
                attpad[((size_t)b * PADROW) + (size_t)(l0 + rl + 1) * 512 + h * 64 + j * 16 + ln]
                    = f2bf(o[g][j][r] * ib);
        }
    }
}

// ---------------------------------------------------------------- launcher
extern "C" void kernel_launch(void* const* d_in, const int* in_sizes, int n_in,
                              void* d_out, int out_size, void* d_ws, size_t ws_size,
                              hipStream_t stream)
{
    const float* x    = (const float*)d_in[0];
    const float* Wq   = (const float*)d_in[1];
    const float* Wk   = (const float*)d_in[2];
    const float* Wv   = (const float*)d_in[3];
    const float* cw   = (const float*)d_in[4];   // [1536][512] flat fp32
    const float* cb   = (const float*)d_in[5];
    const float* mw   = (const float*)d_in[6];
    const float* mb2  = (const float*)d_in[7];
    const int*   sidx = (const int*)d_in[8];
    float* out = (float*)d_out;

    char* ws = (char*)d_ws;
    unsigned short* xb    = (unsigned short*)(ws + 0);           // 33,554,432 B
    unsigned short* Pool  = (unsigned short*)(ws + 0);           // alias (xb dead post-attn)
    unsigned short* Pad   = (unsigned short*)(ws + 33554432);    // 33,570,816 B
    unsigned short* xkg   = (unsigned short*)(ws + 33554432);    // alias Pad head
    unsigned short* xvg   = (unsigned short*)(ws + 37748736);    // alias
    unsigned short* Vg    = (unsigned short*)(ws + 41943040);    // alias
    unsigned short* Kg    = (unsigned short*)(ws + 67125248);    //  4,194,304 B
    unsigned short* Vt    = (unsigned short*)(ws + 71319552);    //  4,194,304 B
    unsigned short* WqT   = (unsigned short*)(ws + 75513856);    //    524,288 B
    unsigned short* WkT   = (unsigned short*)(ws + 76038144);
    unsigned short* WvT   = (unsigned short*)(ws + 76562432);
    unsigned short* CombT = (unsigned short*)(ws + 77086720);
    unsigned short* ConvT = (unsigned short*)(ws + 77611008);    // 1,572,864 B -> end 79,183,872

    dim3 blk(256);

    // 0. x -> bf16
    cvt_bf16<<<dim3(8192), blk, 0, stream>>>(x, xb);

    // 1. weight transposes (fp32 -> bf16): dst[N][K] = W[K][N]
    tr_f32_bf16<<<dim3(8, 8),  blk, 0, stream>>>(WqT,   Wq, 512, 512);
    tr_f32_bf16<<<dim3(8, 8),  blk, 0, stream>>>(WkT,   Wk, 512, 512);
    tr_f32_bf16<<<dim3(8, 8),  blk, 0, stream>>>(WvT,   Wv, 512, 512);
    tr_f32_bf16<<<dim3(8, 8),  blk, 0, stream>>>(CombT, mw, 512, 512);
    tr_f32_bf16<<<dim3(8, 24), blk, 0, stream>>>(ConvT, cw, 1536, 512);

    // 2. gathers (xkg/xvg in Pad head; consumed before zero_pad/attn)
    gather_rows<<<dim3(4096), blk, 0, stream>>>(xb, sidx, xkg, xvg);

    // 3. K/V projections (per-batch 512 gathered rows)
    gemm128<0><<<dim3(4, 32), blk, 0, stream>>>(xkg, WkT, nullptr, Kg, 512);
    gemm128<0><<<dim3(4, 32), blk, 0, stream>>>(xvg, WvT, nullptr, Vg, 512);

    // 4. Vt[b][e][s] = Vg[b][s][e]
    tr_bf16<<<dim3(8, 8, 8), blk, 0, stream>>>(Vt, Vg, 512, 512);

    // 5. attention (M=256 flash, 8-wave blocks, LDS-shared K/V; writes Pad rows 1..L)
    zero_pad<<<dim3(16), blk, 0, stream>>>(Pad);
    attn_fused<<<dim3(16, 8, 8), dim3(512), 0, stream>>>(xb, WqT, Kg, Vt, Pad);

    // 6. conv (K=1536) + bias + ELU + pool -> Pool (aliases dead xb)
    gemm128<1><<<dim3(4, 256), blk, 0, stream>>>(Pad, ConvT, cb, Pool, 1536);

    // 7. final dense + bias -> out (fp32)
    gemm128<2><<<dim3(4, 128), blk, 0, stream>>>(Pool, CombT, mb2, out, 512);
}

// Round 7
// 383.984 us; speedup vs baseline: 1.0781x; 1.0781x over previous
//
#include <hip/hip_runtime.h>

// ProbAttention on MI355X (gfx950). Inputs/outputs fp32; compute in bf16 MFMA
// (mfma_f32_16x16x32_bf16, fp32 accumulate). B=8, L=4096, D=512, H=8, DK=64,
// S=512, CONV_K=3, POOL=2.
//
// attn v9: v4 structure exactly (256 thr / 4 waves / M=128, full-width
// Pp[128][136], ONE lgkmcnt drain + one PV sweep per chunk — best measured:
// 133.6 us; occupancy experiments v6-v8 all failed to move residency off
// ~2 blocks/CU) + two VALU critical-path cuts, both fp32/pack-level with NO
// bf16 requantization (the v5 failure was QKSCALE folded into bf16 Q):
//  1) exp2-direct: score scale constant becomes 0.125*log2(e) (same mul
//     count, fp32), exp/alpha via v_exp (exp2) directly — deletes the
//     64 hidden log2e muls per chunk inside __expf.
//  2) P pack via v_cvt_pk_bf16_f32 (src0 -> low half; RNE, same rounding as
//     the software f2bf): 64 packs x 3 ops -> 16 cvt_pk ops per chunk.
// VALU ops/chunk/thread ~380 -> ~145. VALUBusy was 2x MfmaUtil (32 vs 16) —
// the VALU chain is the critical path at 2 waves/SIMD.

typedef __attribute__((ext_vector_type(8))) short  short8;
typedef __attribute__((ext_vector_type(4))) short  short4b;
typedef __attribute__((ext_vector_type(4))) float  f32x4;

#define LSEQ   4096
#define SK     512
#define EDIM   512
#define LPAD   4098            // L + 2
#define PADROW 2098176         // LPAD * 512 (shorts)
#define SCALE2 0.180336880f    // 0.125 * log2(e) — fp32 score scale for exp2

static __device__ __forceinline__ float bf2f(unsigned short h) {
    union { unsigned int u; float f; } v; v.u = ((unsigned int)h) << 16; return v.f;
}
static __device__ __forceinline__ unsigned short f2bf(float f) {
    union { float f; unsigned int u; } v; v.f = f;
    unsigned int r = (v.u + 0x7fffu + ((v.u >> 16) & 1u)) >> 16;
    return (unsigned short)r;
}
static __device__ __forceinline__ unsigned int cvt_pk_bf16(float lo, float hi) {
    unsigned int r;
    asm("v_cvt_pk_bf16_f32 %0, %1, %2" : "=v"(r) : "v"(lo), "v"(hi));
    return r;   // dst[15:0] = bf16(lo), dst[31:16] = bf16(hi)
}

// ---------------------------------------------------------------- fp32 -> bf16
__global__ __launch_bounds__(256)
void cvt_bf16(const float* __restrict__ src, unsigned short* __restrict__ dst)
{
    const size_t i = ((size_t)blockIdx.x * 256 + threadIdx.x) * 8;
    const float4 a = *(const float4*)(src + i);
    const float4 b = *(const float4*)(src + i + 4);
    short8 o;
    o[0] = (short)f2bf(a.x); o[1] = (short)f2bf(a.y);
    o[2] = (short)f2bf(a.z); o[3] = (short)f2bf(a.w);
    o[4] = (short)f2bf(b.x); o[5] = (short)f2bf(b.y);
    o[6] = (short)f2bf(b.z); o[7] = (short)f2bf(b.w);
    *(short8*)(dst + i) = o;
}

// ---------------------------------------------------------------- transpose fp32 -> bf16
__global__ __launch_bounds__(256)
void tr_f32_bf16(unsigned short* __restrict__ dst, const float* __restrict__ src,
                 int R, int C)
{
    __shared__ unsigned short T[64][72];
    const int t  = threadIdx.x;
    const int r0 = blockIdx.y * 64, c0 = blockIdx.x * 64;
    const int row = t >> 2, cg = (t & 3) * 16;
    const float* s = src + (size_t)(r0 + row) * C + c0 + cg;
    const float4 f0 = *(const float4*)s;
    const float4 f1 = *(const float4*)(s + 4);
    const float4 f2 = *(const float4*)(s + 8);
    const float4 f3 = *(const float4*)(s + 12);
    T[row][cg + 0]  = f2bf(f0.x); T[row][cg + 1]  = f2bf(f0.y);
    T[row][cg + 2]  = f2bf(f0.z); T[row][cg + 3]  = f2bf(f0.w);
    T[row][cg + 4]  = f2bf(f1.x); T[row][cg + 5]  = f2bf(f1.y);
    T[row][cg + 6]  = f2bf(f1.z); T[row][cg + 7]  = f2bf(f1.w);
    T[row][cg + 8]  = f2bf(f2.x); T[row][cg + 9]  = f2bf(f2.y);
    T[row][cg + 10] = f2bf(f2.z); T[row][cg + 11] = f2bf(f2.w);
    T[row][cg + 12] = f2bf(f3.x); T[row][cg + 13] = f2bf(f3.y);
    T[row][cg + 14] = f2bf(f3.z); T[row][cg + 15] = f2bf(f3.w);
    __syncthreads();
    unsigned short* d = dst + (size_t)(c0 + row) * R + r0 + cg;
    short8 o0, o1;
    #pragma unroll
    for (int k = 0; k < 8; ++k) o0[k] = (short)T[cg + k][row];
    #pragma unroll
    for (int k = 0; k < 8; ++k) o1[k] = (short)T[cg + 8 + k][row];
    *(short8*)d       = o0;
    *(short8*)(d + 8) = o1;
}

// ---------------------------------------------------------------- transpose bf16
__global__ __launch_bounds__(256)
void tr_bf16(unsigned short* __restrict__ dst, const unsigned short* __restrict__ src,
             int R, int C)
{
    __shared__ unsigned short T[64][72];
    const size_t bofs = (size_t)blockIdx.z * (size_t)R * (size_t)C;
    src += bofs; dst += bofs;
    const int t  = threadIdx.x;
    const int r0 = blockIdx.y * 64, c0 = blockIdx.x * 64;
    const int row = t >> 2, cg = (t & 3) * 16;
    const unsigned short* s = src + (size_t)(r0 + row) * C + c0 + cg;
    *(short8*)&T[row][cg]     = *(const short8*)s;
    *(short8*)&T[row][cg + 8] = *(const short8*)(s + 8);
    __syncthreads();
    unsigned short* d = dst + (size_t)(c0 + row) * R + r0 + cg;
    short8 o0, o1;
    #pragma unroll
    for (int k = 0; k < 8; ++k) o0[k] = (short)T[cg + k][row];
    #pragma unroll
    for (int k = 0; k < 8; ++k) o1[k] = (short)T[cg + 8 + k][row];
    *(short8*)d       = o0;
    *(short8*)(d + 8) = o1;
}

// ---------------------------------------------------------------- gather rows (bf16)
__global__ __launch_bounds__(256)
void gather_rows(const unsigned short* __restrict__ xb, const int* __restrict__ sidx,
                 unsigned short* __restrict__ xkg, unsigned short* __restrict__ xvg)
{
    const int blk = blockIdx.x;
    const int b = blk >> 9, j = blk & 511;
    const int t = threadIdx.x;
    int qv = sidx[j];               qv = qv < 0 ? 0 : (qv > LSEQ - 1 ? LSEQ - 1 : qv);
    int cv = qv < SK - 1 ? qv : SK - 1;
    int pv = sidx[cv];              pv = pv < 0 ? 0 : (pv > LSEQ - 1 ? LSEQ - 1 : pv);
    const unsigned int* xs = (const unsigned int*)xb;
    unsigned int* kd = (unsigned int*)xkg;
    unsigned int* vd = (unsigned int*)xvg;
    const size_t dst = ((size_t)b * SK + j) * 256 + t;
    kd[dst] = xs[((size_t)b * LSEQ + pv) * 256 + t];
    vd[dst] = xs[((size_t)b * LSEQ + qv) * 256 + t];
}

// ---------------------------------------------------------------- zero pad rows
__global__ __launch_bounds__(256)
void zero_pad(unsigned short* __restrict__ attpad)
{
    const int i = blockIdx.x * 256 + threadIdx.x;   // 0..4095
    const int b = i >> 9, c = i & 511;
    attpad[(size_t)b * PADROW + c] = 0;
    attpad[(size_t)b * PADROW + (size_t)(LPAD - 1) * 512 + c] = 0;
}

// ---------------------------------------------------------------- GEMM 128x128x32
// MODE 0: bf16 store. MODE 1: conv epilogue (+bias, ELU, MaxPool2 -> bf16).
// MODE 2: +bias, fp32 store.
template<int MODE>
__global__ __launch_bounds__(256)
void gemm128(const unsigned short* __restrict__ A, const unsigned short* __restrict__ Bt,
             const float* __restrict__ bias, void* __restrict__ Cout, int K)
{
    __shared__ unsigned short As[128 * 40];
    __shared__ unsigned short Bs[128 * 40];
    const int t    = threadIdx.x;
    const int n0   = blockIdx.x * 128;
    const int m0   = blockIdx.y * 128;
    const int srow = t >> 1, scg = (t & 1) * 16;
    const int lane = t & 63, wv = t >> 6;
    const int q = lane >> 4, ln = lane & 15;
    const int wm = (wv & 1) * 64, wn = (wv >> 1) * 64;

    const unsigned short* abase;
    if (MODE == 1) {
        const int gr = m0 + srow;
        abase = A + (size_t)(gr >> 12) * PADROW + (size_t)(gr & 4095) * 512;
    } else {
        abase = A + (size_t)(m0 + srow) * K;
    }
    const unsigned short* bbase = Bt + (size_t)(n0 + srow) * K;

    const f32x4 zero = {0.f, 0.f, 0.f, 0.f};
    f32x4 acc[4][4];
    #pragma unroll
    for (int i = 0; i < 4; ++i)
        #pragma unroll
        for (int j = 0; j < 4; ++j) acc[i][j] = zero;

    short8 av0 = *(const short8*)(abase + scg);
    short8 av1 = *(const short8*)(abase + scg + 8);
    short8 bv0 = *(const short8*)(bbase + scg);
    short8 bv1 = *(const short8*)(bbase + scg + 8);

    for (int k0 = 0; k0 < K; k0 += 32) {
        __syncthreads();
        *(short8*)&As[srow * 40 + scg]     = av0;
        *(short8*)&As[srow * 40 + scg + 8] = av1;
        *(short8*)&Bs[srow * 40 + scg]     = bv0;
        *(short8*)&Bs[srow * 40 + scg + 8] = bv1;
        __syncthreads();
        if (k0 + 32 < K) {
            av0 = *(const short8*)(abase + k0 + 32 + scg);
            av1 = *(const short8*)(abase + k0 + 32 + scg + 8);
            bv0 = *(const short8*)(bbase + k0 + 32 + scg);
            bv1 = *(const short8*)(bbase + k0 + 32 + scg + 8);
        }
        short8 af[4], bf[4];
        #pragma unroll
        for (int mt = 0; mt < 4; ++mt)
            af[mt] = *(const short8*)&As[(wm + mt * 16 + ln) * 40 + q * 8];
        #pragma unroll
        for (int nt = 0; nt < 4; ++nt)
            bf[nt] = *(const short8*)&Bs[(wn + nt * 16 + ln) * 40 + q * 8];
        #pragma unroll
        for (int mt = 0; mt < 4; ++mt)
            #pragma unroll
            for (int nt = 0; nt < 4; ++nt)
                acc[mt][nt] = __builtin_amdgcn_mfma_f32_16x16x32_bf16(af[mt], bf[nt], acc[mt][nt], 0, 0, 0);
    }

    if (MODE == 0) {
        unsigned short* C = (unsigned short*)Cout;
        #pragma unroll
        for (int mt = 0; mt < 4; ++mt)
            #pragma unroll
            for (int r = 0; r < 4; ++r) {
                const int grow = m0 + wm + mt * 16 + q * 4 + r;
                unsigned short* cp = C + (size_t)grow * 512 + n0 + wn + ln;
                #pragma unroll
                for (int nt = 0; nt < 4; ++nt) cp[nt * 16] = f2bf(acc[mt][nt][r]);
            }
    } else if (MODE == 2) {
        float* C = (float*)Cout;
        float bb[4];
        #pragma unroll
        for (int nt = 0; nt < 4; ++nt) bb[nt] = bias[n0 + wn + nt * 16 + ln];
        #pragma unroll
        for (int mt = 0; mt < 4; ++mt)
            #pragma unroll
            for (int r = 0; r < 4; ++r) {
                const int grow = m0 + wm + mt * 16 + q * 4 + r;
                float* cp = C + (size_t)grow * 512 + n0 + wn + ln;
                #pragma unroll
                for (int nt = 0; nt < 4; ++nt) cp[nt * 16] = acc[mt][nt][r] + bb[nt];
            }
    } else { // MODE 1
        unsigned short* C = (unsigned short*)Cout;
        float bb[4];
        #pragma unroll
        for (int nt = 0; nt < 4; ++nt) bb[nt] = bias[n0 + wn + nt * 16 + ln];
        #pragma unroll
        for (int mt = 0; mt < 4; ++mt) {
            const int grow = m0 + wm + mt * 16 + q * 4;
            const int b = grow >> 12, l = grow & 4095;
            unsigned short* cp = C + ((size_t)b * 2048 + (l >> 1)) * 512 + n0 + wn + ln;
            #pragma unroll
            for (int nt = 0; nt < 4; ++nt) {
                float v0 = acc[mt][nt][0] + bb[nt]; v0 = v0 > 0.f ? v0 : __expf(v0) - 1.f;
                float v1 = acc[mt][nt][1] + bb[nt]; v1 = v1 > 0.f ? v1 : __expf(v1) - 1.f;
                float v2 = acc[mt][nt][2] + bb[nt]; v2 = v2 > 0.f ? v2 : __expf(v2) - 1.f;
                float v3 = acc[mt][nt][3] + bb[nt]; v3 = v3 > 0.f ? v3 : __expf(v3) - 1.f;
                cp[nt * 16]       = f2bf(fmaxf(v0, v1));
                cp[512 + nt * 16] = f2bf(fmaxf(v2, v3));
            }
        }
    }
}

// ---------------------------------------------------------------- fused attention v9
// grid (L/128, H, B), 256 threads = 4 waves; wave w owns 32 q-rows (2 tiles).
// S in 4 chunks of 128, online softmax in base-2 domain: scores scaled by
// 0.125*log2(e) in fp32 (one rounding; replaces 0.125-mul + hidden log2e mul
// in __expf), p = exp2(st - m2), alpha = exp2(dm2) — mathematically identical
// to v4's exp(0.125*s - m), ulp-level fp32 differences only. P packed with
// v_cvt_pk_bf16_f32 (RNE, src0 -> low half) — same bytes/addresses as the
// f2bf short4b stores it replaces. K chunk (128x64) and V chunk (64x128) in
// LDS shared by all 4 waves; next chunk register-prefetched during softmax/PV;
// full-width Pp round-trip, ONE lgkmcnt drain + one PV sweep per chunk.
// LDS = 18,432 + 17,408 + 34,816 = 70,656 B (v4 footprint, 2 blocks/CU).
__global__ __launch_bounds__(256, 2)
void attn_fused(const unsigned short* __restrict__ xb, const unsigned short* __restrict__ WqT,
                const unsigned short* __restrict__ Kg, const unsigned short* __restrict__ Vt,
                unsigned short* __restrict__ attpad)
{
    __shared__ unsigned short Ks[128][72];
    __shared__ unsigned short Vs[64][136];
    __shared__ unsigned short Pp[128][136];   // P per chunk; also Q round-trip
    const int t = threadIdx.x;
    const int wv = t >> 6, lane = t & 63, q = lane >> 4, ln = lane & 15;
    const int l0 = blockIdx.x * 128, h = blockIdx.y, b = blockIdx.z;
    const int qr0 = wv * 32;
    const f32x4 zero = {0.f, 0.f, 0.f, 0.f};

    // staging maps
    const unsigned short* kgb = Kg + (size_t)b * SK * 512 + h * 64;        // + s*512 + e
    const unsigned short* vtb = Vt + ((size_t)(b * EDIM + h * 64)) * SK;   // + d*SK + s
    const int ksr = t >> 1, ksc = (t & 1) * 32;    // K: row s, 32-short half
    const int vsr = t >> 2, vsc = (t & 3) * 32;    // V: row d, 32-short quarter

    // prefetch chunk 0 (flies during Q projection)
    short8 kp0, kp1, kp2, kp3, vp0, vp1, vp2, vp3;
    {
        const unsigned short* ks = kgb + (size_t)ksr * 512 + ksc;
        kp0 = *(const short8*)ks;        kp1 = *(const short8*)(ks + 8);
        kp2 = *(const short8*)(ks + 16); kp3 = *(const short8*)(ks + 24);
        const unsigned short* vs = vtb + (size_t)vsr * SK + vsc;
        vp0 = *(const short8*)vs;        vp1 = *(const short8*)(vs + 8);
        vp2 = *(const short8*)(vs + 16); vp3 = *(const short8*)(vs + 24);
    }

    // --- Q projection: rows qr0 + g*16 + ln (g=0,1), 64 head cols, k=512
    f32x4 qacc[2][4];
    #pragma unroll
    for (int g = 0; g < 2; ++g)
        #pragma unroll
        for (int nt = 0; nt < 4; ++nt) qacc[g][nt] = zero;
    const unsigned short* xr0 = xb + ((size_t)(b * LSEQ + l0 + qr0 + ln)) * 512 + q * 8;
    const unsigned short* xr1 = xr0 + (size_t)16 * 512;
    const unsigned short* wqp = WqT + ((size_t)(h * 64 + ln)) * 512 + q * 8;
    for (int ks = 0; ks < 16; ++ks) {
        const short8 ax0 = *(const short8*)(xr0 + ks * 32);
        const short8 ax1 = *(const short8*)(xr1 + ks * 32);
        #pragma unroll
        for (int nt = 0; nt < 4; ++nt) {
            const short8 bw = *(const short8*)(wqp + nt * 16 * 512 + ks * 32);
            qacc[0][nt] = __builtin_amdgcn_mfma_f32_16x16x32_bf16(ax0, bw, qacc[0][nt], 0, 0, 0);
            qacc[1][nt] = __builtin_amdgcn_mfma_f32_16x16x32_bf16(ax1, bw, qacc[1][nt], 0, 0, 0);
        }
    }
    #pragma unroll
    for (int g = 0; g < 2; ++g)
        #pragma unroll
        for (int nt = 0; nt < 4; ++nt)
            #pragma unroll
            for (int r = 0; r < 4; ++r)
                Pp[qr0 + g * 16 + q * 4 + r][nt * 16 + ln] = f2bf(qacc[g][nt][r]);
    asm volatile("s_waitcnt lgkmcnt(0)" ::: "memory");   // wave-private round trip
    short8 bq[2][2];
    #pragma unroll
    for (int g = 0; g < 2; ++g) {
        bq[g][0] = *(const short8*)&Pp[qr0 + g * 16 + ln][q * 8];
        bq[g][1] = *(const short8*)&Pp[qr0 + g * 16 + ln][q * 8 + 32];
    }

    // --- flash state in base-2 domain (per q-col = ln, per group g)
    float m_run[2] = {-1e30f, -1e30f}, l_run[2] = {0.f, 0.f};
    f32x4 o[2][4];
    #pragma unroll
    for (int g = 0; g < 2; ++g)
        #pragma unroll
        for (int j = 0; j < 4; ++j) o[g][j] = zero;

    for (int c = 0; c < 4; ++c) {
        // store staged chunk (regs were prefetched)
        *(short8*)&Ks[ksr][ksc]      = kp0;  *(short8*)&Ks[ksr][ksc + 8]  = kp1;
        *(short8*)&Ks[ksr][ksc + 16] = kp2;  *(short8*)&Ks[ksr][ksc + 24] = kp3;
        *(short8*)&Vs[vsr][vsc]      = vp0;  *(short8*)&Vs[vsr][vsc + 8]  = vp1;
        *(short8*)&Vs[vsr][vsc + 16] = vp2;  *(short8*)&Vs[vsr][vsc + 24] = vp3;
        __syncthreads();   // A: Ks/Vs ready

        // scores (transposed, pre-scaled by 0.125*log2e):
        // St[s = mt*16+quad*4+r][qcol = g*16+ln]
        f32x4 st[8][2];
        #pragma unroll
        for (int mt = 0; mt < 8; ++mt) {
            const short8 ak0 = *(const short8*)&Ks[mt * 16 + ln][q * 8];
            const short8 ak1 = *(const short8*)&Ks[mt * 16 + ln][q * 8 + 32];
            #pragma unroll
            for (int g = 0; g < 2; ++g) {
                f32x4 a = zero;
                a = __builtin_amdgcn_mfma_f32_16x16x32_bf16(ak0, bq[g][0], a, 0, 0, 0);
                a = __builtin_amdgcn_mfma_f32_16x16x32_bf16(ak1, bq[g][1], a, 0, 0, 0);
                #pragma unroll
                for (int r = 0; r < 4; ++r) a[r] *= SCALE2;
                st[mt][g] = a;
            }
        }

        // online softmax (base-2): max, alpha, exp2 + cvt_pk pack, l fold
        float alpha_[2];
        #pragma unroll
        for (int g = 0; g < 2; ++g) {
            float mx = st[0][g][0];
            #pragma unroll
            for (int mt = 0; mt < 8; ++mt)
                #pragma unroll
                for (int r = 0; r < 4; ++r) mx = fmaxf(mx, st[mt][g][r]);
            mx = fmaxf(mx, __shfl_xor(mx, 16));
            mx = fmaxf(mx, __shfl_xor(mx, 32));
            const float m_new = fmaxf(m_run[g], mx);
            alpha_[g] = __builtin_amdgcn_exp2f(m_run[g] - m_new);
            m_run[g] = m_new;
            float ls = 0.f;
            #pragma unroll
            for (int mt = 0; mt < 8; ++mt) {
                const float p0 = __builtin_amdgcn_exp2f(st[mt][g][0] - m_new);
                const float p1 = __builtin_amdgcn_exp2f(st[mt][g][1] - m_new);
                const float p2 = __builtin_amdgcn_exp2f(st[mt][g][2] - m_new);
                const float p3 = __builtin_amdgcn_exp2f(st[mt][g][3] - m_new);
                ls += (p0 + p1) + (p2 + p3);
                uint2 pw;
                pw.x = cvt_pk_bf16(p0, p1);
                pw.y = cvt_pk_bf16(p2, p3);
                *(uint2*)&Pp[qr0 + g * 16 + ln][mt * 16 + q * 4] = pw;
            }
            ls += __shfl_xor(ls, 16);
            ls += __shfl_xor(ls, 32);
            l_run[g] = l_run[g] * alpha_[g] + ls;
        }

        // rescale O (rows q' = quad*4+r of tile g)
        #pragma unroll
        for (int g = 0; g < 2; ++g) {
            #pragma unroll
            for (int r = 0; r < 4; ++r) {
                const float ab = __shfl(alpha_[g], q * 4 + r);
                #pragma unroll
                for (int j = 0; j < 4; ++j) o[g][j][r] *= ab;
            }
        }

        // prefetch next chunk into regs (overlaps PV)
        if (c < 3) {
            const unsigned short* ks = kgb + (size_t)((c + 1) * 128 + ksr) * 512 + ksc;
            kp0 = *(const short8*)ks;        kp1 = *(const short8*)(ks + 8);
            kp2 = *(const short8*)(ks + 16); kp3 = *(const short8*)(ks + 24);
            const unsigned short* vs = vtb + (size_t)vsr * SK + (c + 1) * 128 + vsc;
            vp0 = *(const short8*)vs;        vp1 = *(const short8*)(vs + 8);
            vp2 = *(const short8*)(vs + 16); vp3 = *(const short8*)(vs + 24);
        }

        asm volatile("s_waitcnt lgkmcnt(0)" ::: "memory");   // P visible to wave

        // PV: A = P rows (q), B = Vs rows (d), k = 128 chunk
        #pragma unroll
        for (int ks2 = 0; ks2 < 4; ++ks2) {
            const short8 ap0 = *(const short8*)&Pp[qr0 + ln][ks2 * 32 + q * 8];
            const short8 ap1 = *(const short8*)&Pp[qr0 + 16 + ln][ks2 * 32 + q * 8];
            #pragma unroll
            for (int j = 0; j < 4; ++j) {
                const short8 bv = *(const short8*)&Vs[j * 16 + ln][ks2 * 32 + q * 8];
                o[0][j] = __builtin_amdgcn_mfma_f32_16x16x32_bf16(ap0, bv, o[0][j], 0, 0, 0);
                o[1][j] = __builtin_amdgcn_mfma_f32_16x16x32_bf16(ap1, bv, o[1][j], 0, 0, 0);
            }
        }
        __syncthreads();   // B: Ks/Vs reads done before restage
    }

    // epilogue: scale by 1/l, store rows l0+qr0+g*16+q*4+r (+1 pad offset)
    #pragma unroll
    for (int g = 0; g < 2; ++g) {
        const float li = 1.f / l_run[g];
        #pragma unroll
        for (int r = 0; r < 4; ++r) {
            const float ib = __shfl(li, q * 4 + r);
            const int rl = qr0 + g * 16 + q * 4 + r;
            #pragma unroll
            for (int j = 0; j < 4; ++j)
                attpad[((size_t)b * PADROW) + (size_t)(l0 + rl + 1) * 512 + h * 64 + j * 16 + ln]
                    = f2bf(o[g][j][r] * ib);
        }
    }
}

// ---------------------------------------------------------------- launcher
extern "C" void kernel_launch(void* const* d_in, const int* in_sizes, int n_in,
                              void* d_out, int out_size, void* d_ws, size_t ws_size,
                              hipStream_t stream)
{
    const float* x    = (const float*)d_in[0];
    const float* Wq   = (const float*)d_in[1];
    const float* Wk   = (const float*)d_in[2];
    const float* Wv   = (const float*)d_in[3];
    const float* cw   = (const float*)d_in[4];   // [1536][512] flat fp32
    const float* cb   = (const float*)d_in[5];
    const float* mw   = (const float*)d_in[6];
    const float* mb2  = (const float*)d_in[7];
    const int*   sidx = (const int*)d_in[8];
    float* out = (float*)d_out;

    char* ws = (char*)d_ws;
    unsigned short* xb    = (unsigned short*)(ws + 0);           // 33,554,432 B
    unsigned short* Pool  = (unsigned short*)(ws + 0);           // alias (xb dead post-attn)
    unsigned short* Pad   = (unsigned short*)(ws + 33554432);    // 33,570,816 B
    unsigned short* xkg   = (unsigned short*)(ws + 33554432);    // alias Pad head
    unsigned short* xvg   = (unsigned short*)(ws + 37748736);    // alias
    unsigned short* Vg    = (unsigned short*)(ws + 41943040);    // alias
    unsigned short* Kg    = (unsigned short*)(ws + 67125248);    //  4,194,304 B
    unsigned short* Vt    = (unsigned short*)(ws + 71319552);    //  4,194,304 B
    unsigned short* WqT   = (unsigned short*)(ws + 75513856);    //    524,288 B
    unsigned short* WkT   = (unsigned short*)(ws + 76038144);
    unsigned short* WvT   = (unsigned short*)(ws + 76562432);
    unsigned short* CombT = (unsigned short*)(ws + 77086720);
    unsigned short* ConvT = (unsigned short*)(ws + 77611008);    // 1,572,864 B -> end 79,183,872

    dim3 blk(256);

    // 0. x -> bf16
    cvt_bf16<<<dim3(8192), blk, 0, stream>>>(x, xb);

    // 1. weight transposes (fp32 -> bf16): dst[N][K] = W[K][N]
    tr_f32_bf16<<<dim3(8, 8),  blk, 0, stream>>>(WqT,   Wq, 512, 512);
    tr_f32_bf16<<<dim3(8, 8),  blk, 0, stream>>>(WkT,   Wk, 512, 512);
    tr_f32_bf16<<<dim3(8, 8),  blk, 0, stream>>>(WvT,   Wv, 512, 512);
    tr_f32_bf16<<<dim3(8, 8),  blk, 0, stream>>>(CombT, mw, 512, 512);
    tr_f32_bf16<<<dim3(8, 24), blk, 0, stream>>>(ConvT, cw, 1536, 512);

    // 2. gathers (xkg/xvg in Pad head; consumed before zero_pad/attn)
    gather_rows<<<dim3(4096), blk, 0, stream>>>(xb, sidx, xkg, xvg);

    // 3. K/V projections (per-batch 512 gathered rows)
    gemm128<0><<<dim3(4, 32), blk, 0, stream>>>(xkg, WkT, nullptr, Kg, 512);
    gemm128<0><<<dim3(4, 32), blk, 0, stream>>>(xvg, WvT, nullptr, Vg, 512);

    // 4. Vt[b][e][s] = Vg[b][s][e]
    tr_bf16<<<dim3(8, 8, 8), blk, 0, stream>>>(Vt, Vg, 512, 512);

    // 5. attention (M=128 flash, LDS-shared K/V; writes Pad rows 1..L)
    zero_pad<<<dim3(16), blk, 0, stream>>>(Pad);
    attn_fused<<<dim3(32, 8, 8), blk, 0, stream>>>(xb, WqT, Kg, Vt, Pad);

    // 6. conv (K=1536) + bias + ELU + pool -> Pool (aliases dead xb)
    gemm128<1><<<dim3(4, 256), blk, 0, stream>>>(Pad, ConvT, cb, Pool, 1536);

    // 7. final dense + bias -> out (fp32)
    gemm128<2><<<dim3(4, 128), blk, 0, stream>>>(Pool, CombT, mb2, out, 512);
}

// Round 9
// 381.617 us; speedup vs baseline: 1.0848x; 1.0062x over previous
//
#include <hip/hip_runtime.h>

// ProbAttention on MI355X (gfx950). Inputs/outputs fp32; compute in bf16 MFMA
// (mfma_f32_16x16x32_bf16, fp32 accumulate). B=8, L=4096, D=512, H=8, DK=64,
// S=512, CONV_K=3, POOL=2.
//
// v10 (resubmit; round-8 bench was an infra failure — container acquire):
// attn unchanged from v9 (129.4 us measured; exp2-domain softmax + cvt_pk
// pack). gemm128 rewritten to the m97-class async structure:
//  - global_load_lds width=16 staging (the compiler never auto-emits it;
//    +67% measured on this structure class) into LINEAR double-buffered LDS
//    [2][128][32] (32,768 B), one __syncthreads per K-step (compiler drains
//    vmcnt+lgkmcnt before s_barrier, which makes the buffer handoff safe).
//  - per-lane global source: wave wv / issue i covers rows wv*32+i*16+(l>>2),
//    16B column (l&3)*8 shorts; LDS dest = wave-uniform base + lane*16B.
//  - fragment reads from linear rows (stride 32 shorts) have the same
//    8-slot bank mapping as the old padded-40 layout — conflicts unchanged.
// Conv GEMM (K=1536) is 51.5 GFLOP — as much MFMA work as all of attention;
// this is the biggest unoptimized block of the remaining ~255 us.

typedef __attribute__((ext_vector_type(8))) short  short8;
typedef __attribute__((ext_vector_type(4))) short  short4b;
typedef __attribute__((ext_vector_type(4))) float  f32x4;

#define LSEQ   4096
#define SK     512
#define EDIM   512
#define LPAD   4098            // L + 2
#define PADROW 2098176         // LPAD * 512 (shorts)
#define SCALE2 0.180336880f    // 0.125 * log2(e) — fp32 score scale for exp2

static __device__ __forceinline__ float bf2f(unsigned short h) {
    union { unsigned int u; float f; } v; v.u = ((unsigned int)h) << 16; return v.f;
}
static __device__ __forceinline__ unsigned short f2bf(float f) {
    union { float f; unsigned int u; } v; v.f = f;
    unsigned int r = (v.u + 0x7fffu + ((v.u >> 16) & 1u)) >> 16;
    return (unsigned short)r;
}
static __device__ __forceinline__ unsigned int cvt_pk_bf16(float lo, float hi) {
    unsigned int r;
    asm("v_cvt_pk_bf16_f32 %0, %1, %2" : "=v"(r) : "v"(lo), "v"(hi));
    return r;   // dst[15:0] = bf16(lo), dst[31:16] = bf16(hi)
}
// async global -> LDS, 16 B per lane; LDS dest = wave-uniform base + lane*16
typedef __attribute__((address_space(1))) const unsigned int  gu32;
typedef __attribute__((address_space(3))) unsigned int        lu32;
static __device__ __forceinline__ void g2l16(const unsigned short* g, unsigned short* l)
{
    __builtin_amdgcn_global_load_lds((gu32*)g, (lu32*)l, 16, 0, 0);
}

// ---------------------------------------------------------------- fp32 -> bf16
__global__ __launch_bounds__(256)
void cvt_bf16(const float* __restrict__ src, unsigned short* __restrict__ dst)
{
    const size_t i = ((size_t)blockIdx.x * 256 + threadIdx.x) * 8;
    const float4 a = *(const float4*)(src + i);
    const float4 b = *(const float4*)(src + i + 4);
    short8 o;
    o[0] = (short)f2bf(a.x); o[1] = (short)f2bf(a.y);
    o[2] = (short)f2bf(a.z); o[3] = (short)f2bf(a.w);
    o[4] = (short)f2bf(b.x); o[5] = (short)f2bf(b.y);
    o[6] = (short)f2bf(b.z); o[7] = (short)f2bf(b.w);
    *(short8*)(dst + i) = o;
}

// ---------------------------------------------------------------- transpose fp32 -> bf16
__global__ __launch_bounds__(256)
void tr_f32_bf16(unsigned short* __restrict__ dst, const float* __restrict__ src,
                 int R, int C)
{
    __shared__ unsigned short T[64][72];
    const int t  = threadIdx.x;
    const int r0 = blockIdx.y * 64, c0 = blockIdx.x * 64;
    const int row = t >> 2, cg = (t & 3) * 16;
    const float* s = src + (size_t)(r0 + row) * C + c0 + cg;
    const float4 f0 = *(const float4*)s;
    const float4 f1 = *(const float4*)(s + 4);
    const float4 f2 = *(const float4*)(s + 8);
    const float4 f3 = *(const float4*)(s + 12);
    T[row][cg + 0]  = f2bf(f0.x); T[row][cg + 1]  = f2bf(f0.y);
    T[row][cg + 2]  = f2bf(f0.z); T[row][cg + 3]  = f2bf(f0.w);
    T[row][cg + 4]  = f2bf(f1.x); T[row][cg + 5]  = f2bf(f1.y);
    T[row][cg + 6]  = f2bf(f1.z); T[row][cg + 7]  = f2bf(f1.w);
    T[row][cg + 8]  = f2bf(f2.x); T[row][cg + 9]  = f2bf(f2.y);
    T[row][cg + 10] = f2bf(f2.z); T[row][cg + 11] = f2bf(f2.w);
    T[row][cg + 12] = f2bf(f3.x); T[row][cg + 13] = f2bf(f3.y);
    T[row][cg + 14] = f2bf(f3.z); T[row][cg + 15] = f2bf(f3.w);
    __syncthreads();
    unsigned short* d = dst + (size_t)(c0 + row) * R + r0 + cg;
    short8 o0, o1;
    #pragma unroll
    for (int k = 0; k < 8; ++k) o0[k] = (short)T[cg + k][row];
    #pragma unroll
    for (int k = 0; k < 8; ++k) o1[k] = (short)T[cg + 8 + k][row];
    *(short8*)d       = o0;
    *(short8*)(d + 8) = o1;
}

// ---------------------------------------------------------------- transpose bf16
__global__ __launch_bounds__(256)
void tr_bf16(unsigned short* __restrict__ dst, const unsigned short* __restrict__ src,
             int R, int C)
{
    __shared__ unsigned short T[64][72];
    const size_t bofs = (size_t)blockIdx.z * (size_t)R * (size_t)C;
    src += bofs; dst += bofs;
    const int t  = threadIdx.x;
    const int r0 = blockIdx.y * 64, c0 = blockIdx.x * 64;
    const int row = t >> 2, cg = (t & 3) * 16;
    const unsigned short* s = src + (size_t)(r0 + row) * C + c0 + cg;
    *(short8*)&T[row][cg]     = *(const short8*)s;
    *(short8*)&T[row][cg + 8] = *(const short8*)(s + 8);
    __syncthreads();
    unsigned short* d = dst + (size_t)(c0 + row) * R + r0 + cg;
    short8 o0, o1;
    #pragma unroll
    for (int k = 0; k < 8; ++k) o0[k] = (short)T[cg + k][row];
    #pragma unroll
    for (int k = 0; k < 8; ++k) o1[k] = (short)T[cg + 8 + k][row];
    *(short8*)d       = o0;
    *(short8*)(d + 8) = o1;
}

// ---------------------------------------------------------------- gather rows (bf16)
__global__ __launch_bounds__(256)
void gather_rows(const unsigned short* __restrict__ xb, const int* __restrict__ sidx,
                 unsigned short* __restrict__ xkg, unsigned short* __restrict__ xvg)
{
    const int blk = blockIdx.x;
    const int b = blk >> 9, j = blk & 511;
    const int t = threadIdx.x;
    int qv = sidx[j];               qv = qv < 0 ? 0 : (qv > LSEQ - 1 ? LSEQ - 1 : qv);
    int cv = qv < SK - 1 ? qv : SK - 1;
    int pv = sidx[cv];              pv = pv < 0 ? 0 : (pv > LSEQ - 1 ? LSEQ - 1 : pv);
    const unsigned int* xs = (const unsigned int*)xb;
    unsigned int* kd = (unsigned int*)xkg;
    unsigned int* vd = (unsigned int*)xvg;
    const size_t dst = ((size_t)b * SK + j) * 256 + t;
    kd[dst] = xs[((size_t)b * LSEQ + pv) * 256 + t];
    vd[dst] = xs[((size_t)b * LSEQ + qv) * 256 + t];
}

// ---------------------------------------------------------------- zero pad rows
__global__ __launch_bounds__(256)
void zero_pad(unsigned short* __restrict__ attpad)
{
    const int i = blockIdx.x * 256 + threadIdx.x;   // 0..4095
    const int b = i >> 9, c = i & 511;
    attpad[(size_t)b * PADROW + c] = 0;
    attpad[(size_t)b * PADROW + (size_t)(LPAD - 1) * 512 + c] = 0;
}

// ---------------------------------------------------------------- GEMM 128x128x32
// MODE 0: bf16 store. MODE 1: conv epilogue (+bias, ELU, MaxPool2 -> bf16).
// MODE 2: +bias, fp32 store.
// Staging: global_load_lds dwordx4 into linear double-buffered LDS, one
// barrier per K-step (m97 structure). Wave wv, issue i (0/1) covers rows
// wv*32 + i*16 + (lane>>2), 16B column (lane&3)*8 shorts at k0; LDS dest is
// the wave-uniform base of that 16-row stripe (+ lane*16B by hardware).
template<int MODE>
__global__ __launch_bounds__(256)
void gemm128(const unsigned short* __restrict__ A, const unsigned short* __restrict__ Bt,
             const float* __restrict__ bias, void* __restrict__ Cout, int K)
{
    __shared__ unsigned short As[2][128 * 32];
    __shared__ unsigned short Bs[2][128 * 32];
    const int t    = threadIdx.x;
    const int n0   = blockIdx.x * 128;
    const int m0   = blockIdx.y * 128;
    const int lane = t & 63, wv = t >> 6;
    const int q = lane >> 4, ln = lane & 15;
    const int wm = (wv & 1) * 64, wn = (wv >> 1) * 64;

    // per-lane global row pointers for the two issues of this wave
    const int srl = (wv << 5) + (lane >> 2);     // rows srl and srl+16
    const int scs = (lane & 3) * 8;              // 16B column (shorts)
    const unsigned short* arow0;
    const unsigned short* arow1;
    if (MODE == 1) {
        const int gr0 = m0 + srl;                // block never straddles a batch
        arow0 = A + (size_t)(gr0 >> 12) * PADROW + (size_t)(gr0 & 4095) * 512 + scs;
        arow1 = arow0 + (size_t)16 * 512;
    } else {
        arow0 = A + (size_t)(m0 + srl) * K + scs;
        arow1 = arow0 + (size_t)16 * K;
    }
    const unsigned short* brow0 = Bt + (size_t)(n0 + srl) * K + scs;
    const unsigned short* brow1 = brow0 + (size_t)16 * K;

    // wave-uniform LDS bases (shorts) for the two 16-row stripes
    const int lb0 = (wv << 5) * 32;              // stripe rows wv*32 .. +15
    const int lb1 = lb0 + 16 * 32;               // stripe rows wv*32+16 .. +31

    const f32x4 zero = {0.f, 0.f, 0.f, 0.f};
    f32x4 acc[4][4];
    #pragma unroll
    for (int i = 0; i < 4; ++i)
        #pragma unroll
        for (int j = 0; j < 4; ++j) acc[i][j] = zero;

    // prologue: stage k0 = 0 into buffer 0
    g2l16(arow0, &As[0][lb0]);  g2l16(arow1, &As[0][lb1]);
    g2l16(brow0, &Bs[0][lb0]);  g2l16(brow1, &Bs[0][lb1]);

    for (int k0 = 0; k0 < K; k0 += 32) {
        const int cur = (k0 >> 5) & 1;
        __syncthreads();   // compiler drains vmcnt+lgkmcnt: buf[cur] staged,
                           // and every wave finished its previous-iter reads
        if (k0 + 32 < K) {
            const int nxt = cur ^ 1;
            g2l16(arow0 + k0 + 32, &As[nxt][lb0]);
            g2l16(arow1 + k0 + 32, &As[nxt][lb1]);
            g2l16(brow0 + k0 + 32, &Bs[nxt][lb0]);
            g2l16(brow1 + k0 + 32, &Bs[nxt][lb1]);
        }
        short8 af[4], bf[4];
        #pragma unroll
        for (int mt = 0; mt < 4; ++mt)
            af[mt] = *(const short8*)&As[cur][(wm + mt * 16 + ln) * 32 + q * 8];
        #pragma unroll
        for (int nt = 0; nt < 4; ++nt)
            bf[nt] = *(const short8*)&Bs[cur][(wn + nt * 16 + ln) * 32 + q * 8];
        #pragma unroll
        for (int mt = 0; mt < 4; ++mt)
            #pragma unroll
            for (int nt = 0; nt < 4; ++nt)
                acc[mt][nt] = __builtin_amdgcn_mfma_f32_16x16x32_bf16(af[mt], bf[nt], acc[mt][nt], 0, 0, 0);
    }

    if (MODE == 0) {
        unsigned short* C = (unsigned short*)Cout;
        #pragma unroll
        for (int mt = 0; mt < 4; ++mt)
            #pragma unroll
            for (int r = 0; r < 4; ++r) {
                const int grow = m0 + wm + mt * 16 + q * 4 + r;
                unsigned short* cp = C + (size_t)grow * 512 + n0 + wn + ln;
                #pragma unroll
                for (int nt = 0; nt < 4; ++nt) cp[nt * 16] = f2bf(acc[mt][nt][r]);
            }
    } else if (MODE == 2) {
        float* C = (float*)Cout;
        float bb[4];
        #pragma unroll
        for (int nt = 0; nt < 4; ++nt) bb[nt] = bias[n0 + wn + nt * 16 + ln];
        #pragma unroll
        for (int mt = 0; mt < 4; ++mt)
            #pragma unroll
            for (int r = 0; r < 4; ++r) {
                const int grow = m0 + wm + mt * 16 + q * 4 + r;
                float* cp = C + (size_t)grow * 512 + n0 + wn + ln;
                #pragma unroll
                for (int nt = 0; nt < 4; ++nt) cp[nt * 16] = acc[mt][nt][r] + bb[nt];
            }
    } else { // MODE 1
        unsigned short* C = (unsigned short*)Cout;
        float bb[4];
        #pragma unroll
        for (int nt = 0; nt < 4; ++nt) bb[nt] = bias[n0 + wn + nt * 16 + ln];
        #pragma unroll
        for (int mt = 0; mt < 4; ++mt) {
            const int grow = m0 + wm + mt * 16 + q * 4;
            const int b = grow >> 12, l = grow & 4095;
            unsigned short* cp = C + ((size_t)b * 2048 + (l >> 1)) * 512 + n0 + wn + ln;
            #pragma unroll
            for (int nt = 0; nt < 4; ++nt) {
                float v0 = acc[mt][nt][0] + bb[nt]; v0 = v0 > 0.f ? v0 : __expf(v0) - 1.f;
                float v1 = acc[mt][nt][1] + bb[nt]; v1 = v1 > 0.f ? v1 : __expf(v1) - 1.f;
                float v2 = acc[mt][nt][2] + bb[nt]; v2 = v2 > 0.f ? v2 : __expf(v2) - 1.f;
                float v3 = acc[mt][nt][3] + bb[nt]; v3 = v3 > 0.f ? v3 : __expf(v3) - 1.f;
                cp[nt * 16]       = f2bf(fmaxf(v0, v1));
                cp[512 + nt * 16] = f2bf(fmaxf(v2, v3));
            }
        }
    }
}

// ---------------------------------------------------------------- fused attention v9
// grid (L/128, H, B), 256 threads = 4 waves; wave w owns 32 q-rows (2 tiles).
// S in 4 chunks of 128, online softmax in base-2 domain; P packed with
// v_cvt_pk_bf16_f32. K chunk (128x64) and V chunk (64x128) in LDS shared by
// all 4 waves; next chunk register-prefetched during softmax/PV; full-width
// Pp round-trip, ONE lgkmcnt drain + one PV sweep per chunk.
// LDS = 18,432 + 17,408 + 34,816 = 70,656 B (2 blocks/CU).
__global__ __launch_bounds__(256, 2)
void attn_fused(const unsigned short* __restrict__ xb, const unsigned short* __restrict__ WqT,
                const unsigned short* __restrict__ Kg, const unsigned short* __restrict__ Vt,
                unsigned short* __restrict__ attpad)
{
    __shared__ unsigned short Ks[128][72];
    __shared__ unsigned short Vs[64][136];
    __shared__ unsigned short Pp[128][136];   // P per chunk; also Q round-trip
    const int t = threadIdx.x;
    const int wv = t >> 6, lane = t & 63, q = lane >> 4, ln = lane & 15;
    const int l0 = blockIdx.x * 128, h = blockIdx.y, b = blockIdx.z;
    const int qr0 = wv * 32;
    const f32x4 zero = {0.f, 0.f, 0.f, 0.f};

    // staging maps
    const unsigned short* kgb = Kg + (size_t)b * SK * 512 + h * 64;        // + s*512 + e
    const unsigned short* vtb = Vt + ((size_t)(b * EDIM + h * 64)) * SK;   // + d*SK + s
    const int ksr = t >> 1, ksc = (t & 1) * 32;    // K: row s, 32-short half
    const int vsr = t >> 2, vsc = (t & 3) * 32;    // V: row d, 32-short quarter

    // prefetch chunk 0 (flies during Q projection)
    short8 kp0, kp1, kp2, kp3, vp0, vp1, vp2, vp3;
    {
        const unsigned short* ks = kgb + (size_t)ksr * 512 + ksc;
        kp0 = *(const short8*)ks;        kp1 = *(const short8*)(ks + 8);
        kp2 = *(const short8*)(ks + 16); kp3 = *(const short8*)(ks + 24);
        const unsigned short* vs = vtb + (size_t)vsr * SK + vsc;
        vp0 = *(const short8*)vs;        vp1 = *(const short8*)(vs + 8);
        vp2 = *(const short8*)(vs + 16); vp3 = *(const short8*)(vs + 24);
    }

    // --- Q projection: rows qr0 + g*16 + ln (g=0,1), 64 head cols, k=512
    f32x4 qacc[2][4];
    #pragma unroll
    for (int g = 0; g < 2; ++g)
        #pragma unroll
        for (int nt = 0; nt < 4; ++nt) qacc[g][nt] = zero;
    const unsigned short* xr0 = xb + ((size_t)(b * LSEQ + l0 + qr0 + ln)) * 512 + q * 8;
    const unsigned short* xr1 = xr0 + (size_t)16 * 512;
    const unsigned short* wqp = WqT + ((size_t)(h * 64 + ln)) * 512 + q * 8;
    for (int ks = 0; ks < 16; ++ks) {
        const short8 ax0 = *(const short8*)(xr0 + ks * 32);
        const short8 ax1 = *(const short8*)(xr1 + ks * 32);
        #pragma unroll
        for (int nt = 0; nt < 4; ++nt) {
            const short8 bw = *(const short8*)(wqp + nt * 16 * 512 + ks * 32);
            qacc[0][nt] = __builtin_amdgcn_mfma_f32_16x16x32_bf16(ax0, bw, qacc[0][nt], 0, 0, 0);
            qacc[1][nt] = __builtin_amdgcn_mfma_f32_16x16x32_bf16(ax1, bw, qacc[1][nt], 0, 0, 0);
        }
    }
    #pragma unroll
    for (int g = 0; g < 2; ++g)
        #pragma unroll
        for (int nt = 0; nt < 4; ++nt)
            #pragma unroll
            for (int r = 0; r < 4; ++r)
                Pp[qr0 + g * 16 + q * 4 + r][nt * 16 + ln] = f2bf(qacc[g][nt][r]);
    asm volatile("s_waitcnt lgkmcnt(0)" ::: "memory");   // wave-private round trip
    short8 bq[2][2];
    #pragma unroll
    for (int g = 0; g < 2; ++g) {
        bq[g][0] = *(const short8*)&Pp[qr0 + g * 16 + ln][q * 8];
        bq[g][1] = *(const short8*)&Pp[qr0 + g * 16 + ln][q * 8 + 32];
    }

    // --- flash state in base-2 domain (per q-col = ln, per group g)
    float m_run[2] = {-1e30f, -1e30f}, l_run[2] = {0.f, 0.f};
    f32x4 o[2][4];
    #pragma unroll
    for (int g = 0; g < 2; ++g)
        #pragma unroll
        for (int j = 0; j < 4; ++j) o[g][j] = zero;

    for (int c = 0; c < 4; ++c) {
        // store staged chunk (regs were prefetched)
        *(short8*)&Ks[ksr][ksc]      = kp0;  *(short8*)&Ks[ksr][ksc + 8]  = kp1;
        *(short8*)&Ks[ksr][ksc + 16] = kp2;  *(short8*)&Ks[ksr][ksc + 24] = kp3;
        *(short8*)&Vs[vsr][vsc]      = vp0;  *(short8*)&Vs[vsr][vsc + 8]  = vp1;
        *(short8*)&Vs[vsr][vsc + 16] = vp2;  *(short8*)&Vs[vsr][vsc + 24] = vp3;
        __syncthreads();   // A: Ks/Vs ready

        // scores (transposed, pre-scaled by 0.125*log2e):
        // St[s = mt*16+quad*4+r][qcol = g*16+ln]
        f32x4 st[8][2];
        #pragma unroll
        for (int mt = 0; mt < 8; ++mt) {
            const short8 ak0 = *(const short8*)&Ks[mt * 16 + ln][q * 8];
            const short8 ak1 = *(const short8*)&Ks[mt * 16 + ln][q * 8 + 32];
            #pragma unroll
            for (int g = 0; g < 2; ++g) {
                f32x4 a = zero;
                a = __builtin_amdgcn_mfma_f32_16x16x32_bf16(ak0, bq[g][0], a, 0, 0, 0);
                a = __builtin_amdgcn_mfma_f32_16x16x32_bf16(ak1, bq[g][1], a, 0, 0, 0);
                #pragma unroll
                for (int r = 0; r < 4; ++r) a[r] *= SCALE2;
                st[mt][g] = a;
            }
        }

        // online softmax (base-2): max, alpha, exp2 + cvt_pk pack, l fold
        float alpha_[2];
        #pragma unroll
        for (int g = 0; g < 2; ++g) {
            float mx = st[0][g][0];
            #pragma unroll
            for (int mt = 0; mt < 8; ++mt)
                #pragma unroll
                for (int r = 0; r < 4; ++r) mx = fmaxf(mx, st[mt][g][r]);
            mx = fmaxf(mx, __shfl_xor(mx, 16));
            mx = fmaxf(mx, __shfl_xor(mx, 32));
            const float m_new = fmaxf(m_run[g], mx);
            alpha_[g] = __builtin_amdgcn_exp2f(m_run[g] - m_new);
            m_run[g] = m_new;
            float ls = 0.f;
            #pragma unroll
            for (int mt = 0; mt < 8; ++mt) {
                const float p0 = __builtin_amdgcn_exp2f(st[mt][g][0] - m_new);
                const float p1 = __builtin_amdgcn_exp2f(st[mt][g][1] - m_new);
                const float p2 = __builtin_amdgcn_exp2f(st[mt][g][2] - m_new);
                const float p3 = __builtin_amdgcn_exp2f(st[mt][g][3] - m_new);
                ls += (p0 + p1) + (p2 + p3);
                uint2 pw;
                pw.x = cvt_pk_bf16(p0, p1);
                pw.y = cvt_pk_bf16(p2, p3);
                *(uint2*)&Pp[qr0 + g * 16 + ln][mt * 16 + q * 4] = pw;
            }
            ls += __shfl_xor(ls, 16);
            ls += __shfl_xor(ls, 32);
            l_run[g] = l_run[g] * alpha_[g] + ls;
        }

        // rescale O (rows q' = quad*4+r of tile g)
        #pragma unroll
        for (int g = 0; g < 2; ++g) {
            #pragma unroll
            for (int r = 0; r < 4; ++r) {
                const float ab = __shfl(alpha_[g], q * 4 + r);
                #pragma unroll
                for (int j = 0; j < 4; ++j) o[g][j][r] *= ab;
            }
        }

        // prefetch next chunk into regs (overlaps PV)
        if (c < 3) {
            const unsigned short* ks = kgb + (size_t)((c + 1) * 128 + ksr) * 512 + ksc;
            kp0 = *(const short8*)ks;        kp1 = *(const short8*)(ks + 8);
            kp2 = *(const short8*)(ks + 16); kp3 = *(const short8*)(ks + 24);
            const unsigned short* vs = vtb + (size_t)vsr * SK + (c + 1) * 128 + vsc;
            vp0 = *(const short8*)vs;        vp1 = *(const short8*)(vs + 8);
            vp2 = *(const short8*)(vs + 16); vp3 = *(const short8*)(vs + 24);
        }

        asm volatile("s_waitcnt lgkmcnt(0)" ::: "memory");   // P visible to wave

        // PV: A = P rows (q), B = Vs rows (d), k = 128 chunk
        #pragma unroll
        for (int ks2 = 0; ks2 < 4; ++ks2) {
            const short8 ap0 = *(const short8*)&Pp[qr0 + ln][ks2 * 32 + q * 8];
            const short8 ap1 = *(const short8*)&Pp[qr0 + 16 + ln][ks2 * 32 + q * 8];
            #pragma unroll
            for (int j = 0; j < 4; ++j) {
                const short8 bv = *(const short8*)&Vs[j * 16 + ln][ks2 * 32 + q * 8];
                o[0][j] = __builtin_amdgcn_mfma_f32_16x16x32_bf16(ap0, bv, o[0][j], 0, 0, 0);
                o[1][j] = __builtin_amdgcn_mfma_f32_16x16x32_bf16(ap1, bv, o[1][j], 0, 0, 0);
            }
        }
        __syncthreads();   // B: Ks/Vs reads done before restage
    }

    // epilogue: scale by 1/l, store rows l0+qr0+g*16+q*4+r (+1 pad offset)
    #pragma unroll
    for (int g = 0; g < 2; ++g) {
        const float li = 1.f / l_run[g];
        #pragma unroll
        for (int r = 0; r < 4; ++r) {
            const float ib = __shfl(li, q * 4 + r);
            const int rl = qr0 + g * 16 + q * 4 + r;
            #pragma unroll
            for (int j = 0; j < 4; ++j)
                attpad[((size_t)b * PADROW) + (size_t)(l0 + rl + 1) * 512 + h * 64 + j * 16 + ln]
                    = f2bf(o[g][j][r] * ib);
        }
    }
}

// ---------------------------------------------------------------- launcher
extern "C" void kernel_launch(void* const* d_in, const int* in_sizes, int n_in,
                              void* d_out, int out_size, void* d_ws, size_t ws_size,
                              hipStream_t stream)
{
    const float* x    = (const float*)d_in[0];
    const float* Wq   = (const float*)d_in[1];
    const float* Wk   = (const float*)d_in[2];
    const float* Wv   = (const float*)d_in[3];
    const float* cw   = (const float*)d_in[4];   // [1536][512] flat fp32
    const float* cb   = (const float*)d_in[5];
    const float* mw   = (const float*)d_in[6];
    const float* mb2  = (const float*)d_in[7];
    const int*   sidx = (const int*)d_in[8];
    float* out = (float*)d_out;

    char* ws = (char*)d_ws;
    unsigned short* xb    = (unsigned short*)(ws + 0);           // 33,554,432 B
    unsigned short* Pool  = (unsigned short*)(ws + 0);           // alias (xb dead post-attn)
    unsigned short* Pad   = (unsigned short*)(ws + 33554432);    // 33,570,816 B
    unsigned short* xkg   = (unsigned short*)(ws + 33554432);    // alias Pad head
    unsigned short* xvg   = (unsigned short*)(ws + 37748736);    // alias
    unsigned short* Vg    = (unsigned short*)(ws + 41943040);    // alias
    unsigned short* Kg    = (unsigned short*)(ws + 67125248);    //  4,194,304 B
    unsigned short* Vt    = (unsigned short*)(ws + 71319552);    //  4,194,304 B
    unsigned short* WqT   = (unsigned short*)(ws + 75513856);    //    524,288 B
    unsigned short* WkT   = (unsigned short*)(ws + 76038144);
    unsigned short* WvT   = (unsigned short*)(ws + 76562432);
    unsigned short* CombT = (unsigned short*)(ws + 77086720);
    unsigned short* ConvT = (unsigned short*)(ws + 77611008);    // 1,572,864 B -> end 79,183,872

    dim3 blk(256);

    // 0. x -> bf16
    cvt_bf16<<<dim3(8192), blk, 0, stream>>>(x, xb);

    // 1. weight transposes (fp32 -> bf16): dst[N][K] = W[K][N]
    tr_f32_bf16<<<dim3(8, 8),  blk, 0, stream>>>(WqT,   Wq, 512, 512);
    tr_f32_bf16<<<dim3(8, 8),  blk, 0, stream>>>(WkT,   Wk, 512, 512);
    tr_f32_bf16<<<dim3(8, 8),  blk, 0, stream>>>(WvT,   Wv, 512, 512);
    tr_f32_bf16<<<dim3(8, 8),  blk, 0, stream>>>(CombT, mw, 512, 512);
    tr_f32_bf16<<<dim3(8, 24), blk, 0, stream>>>(ConvT, cw, 1536, 512);

    // 2. gathers (xkg/xvg in Pad head; consumed before zero_pad/attn)
    gather_rows<<<dim3(4096), blk, 0, stream>>>(xb, sidx, xkg, xvg);

    // 3. K/V projections (per-batch 512 gathered rows)
    gemm128<0><<<dim3(4, 32), blk, 0, stream>>>(xkg, WkT, nullptr, Kg, 512);
    gemm128<0><<<dim3(4, 32), blk, 0, stream>>>(xvg, WvT, nullptr, Vg, 512);

    // 4. Vt[b][e][s] = Vg[b][s][e]
    tr_bf16<<<dim3(8, 8, 8), blk, 0, stream>>>(Vt, Vg, 512, 512);

    // 5. attention (M=128 flash, LDS-shared K/V; writes Pad rows 1..L)
    zero_pad<<<dim3(16), blk, 0, stream>>>(Pad);
    attn_fused<<<dim3(32, 8, 8), blk, 0, stream>>>(xb, WqT, Kg, Vt, Pad);

    // 6. conv (K=1536) + bias + ELU + pool -> Pool (aliases dead xb)
    gemm128<1><<<dim3(4, 256), blk, 0, stream>>>(Pad, ConvT, cb, Pool, 1536);

    // 7. final dense + bias -> out (fp32)
    gemm128<2><<<dim3(4, 128), blk, 0, stream>>>(Pool, CombT, mb2, out, 512);
}